// Round 7
// baseline (56.019 us; speedup 1.0000x reference)
//
#include <hip/hip_runtime.h>
#include <hip/hip_fp16.h>

// CompositeBezierCurve: K=4096 segments, degree-7 Bezier (8 cp), D=3.
//   xt  = mod(x_eval[i], x[K]);  seg = searchsorted_right(xstart, xt) - 1
//   s   = (xt - x[seg]) / (x[seg+1] - x[seg]);  out = sum_j B_j(s) cp[seg][j]
//
// R6: ONE scattered line-REQUEST per eval.
//  - 4 consecutive lanes (a TA quad) cooperate on one eval; each lane loads a
//    different 16B chunk of the same 64B line in ONE dwordx4 -> the quad's
//    addresses merge to a single L1 line request.
//  - bucket table FUSED with segment lines: bucket b holds the full 64B line
//    of its conservative segment lo, plus {xb=x[lo+1], lo} in the padding.
//    Bucket width 0.375+2delta < min dx 0.5 => seg in {lo, lo+1}, decided by
//    one compare; ~12% of evals do a masked second load from the seg table.
//  - per-lane work: 2-3 Bernstein weights + 4-8 fp16 FMAs; quad-reduce via
//    __shfl_xor; x0/invdx/xb/lo broadcast via __shfl. Zero LDS.
//
// 64B line layout (16 floats f[0..15], halfs h[i] at byte 2i):
//   chunk0 (f0-3):  h0..h7   = cp[r=0..7]      (r = j*3+d, natural order)
//   chunk1 (f4-7):  h8..h11  = cp[8..11]; f6 = x0; f7 = invdx
//   chunk2 (f8-11): h16..h23 = cp[12..19]
//   chunk3 (f12-15):h24..h27 = cp[20..23]; f14 = xb; u32 f15 = lo

constexpr int K_SEG = 4096;
constexpr int M_BKT = 16384;   // width <= 0.375 < min dx 0.5 => <=1 knot/bucket

__device__ inline int ans_search(const float* __restrict__ x, float v) {
    // largest i in [0, K_SEG-1] with x[i] <= v  (x[0]=0, so v<0 -> 0)
    int lo = 0, hi = K_SEG - 1;
    while (lo < hi) {
        int mid = (lo + hi + 1) >> 1;
        if (x[mid] <= v) lo = mid; else hi = mid - 1;
    }
    return lo;
}

__device__ inline void write_line(float4* __restrict__ dst,
                                  const float* __restrict__ x,
                                  const float* __restrict__ cp,
                                  int seg, float xb, unsigned lov) {
    float f[16];
    __half* h = reinterpret_cast<__half*>(f);
    #pragma unroll
    for (int r = 0; r < 12; ++r) h[r] = __float2half(cp[seg * 24 + r]);      // f0..f5
    float x0 = x[seg];
    f[6] = x0;
    f[7] = 1.0f / (x[seg + 1] - x0);
    #pragma unroll
    for (int r = 12; r < 24; ++r) h[r + 4] = __float2half(cp[seg * 24 + r]); // f8..f13
    f[14] = xb;
    reinterpret_cast<unsigned*>(f)[15] = lov;
    const float4* q = reinterpret_cast<const float4*>(f);
    dst[0] = q[0]; dst[1] = q[1]; dst[2] = q[2]; dst[3] = q[3];
}

__global__ void build_bline(const float* __restrict__ x,
                            const float* __restrict__ cp,
                            float4* __restrict__ bl) {
    int b = blockIdx.x * blockDim.x + threadIdx.x;
    if (b >= M_BKT) return;
    float xlast = x[K_SEG];
    float wq = xlast / (float)M_BKT;        // <= 0.375
    float delta = xlast * 2e-6f;            // >> eval-time rounding of xt*inv
    int lo = ans_search(x, (float)b * wq - delta);
    write_line(bl + b * 4, x, cp, lo, x[lo + 1], (unsigned)lo);
}

__global__ void build_segline(const float* __restrict__ x,
                              const float* __restrict__ cp,
                              float4* __restrict__ sl) {
    int s = blockIdx.x * blockDim.x + threadIdx.x;
    if (s >= K_SEG) return;
    write_line(sl + s * 4, x, cp, s, 3.4e38f, (unsigned)s);
}

__global__ __launch_bounds__(256) void bezier_eval_coop(
    const float* __restrict__ x,
    const float4* __restrict__ bl,
    const float4* __restrict__ sl,
    const float* __restrict__ xe,
    float* __restrict__ out,
    int n)
{
    const float xlast = x[K_SEG];
    const float inv = (float)M_BKT / xlast;
    const int lane  = threadIdx.x & 63;
    const int c     = lane & 3;          // chunk id within quad
    const int gbase = lane & ~3;         // quad base lane
    const int grp   = lane >> 2;         // 0..15: eval slot within wave
    const int wv = (blockIdx.x * blockDim.x + threadIdx.x) >> 6;
    const int nw = (gridDim.x * blockDim.x) >> 6;

    for (int base = wv * 64; base < n; base += nw * 64) {
        #pragma unroll
        for (int u = 0; u < 4; ++u) {
            int e  = base + u * 16 + grp;
            int ec = (e < n) ? e : (n - 1);

            float xv = xe[ec];                               // quad-shared addr
            float xt = (xv >= xlast) ? (xv - xlast) : xv;    // exact np.mod here

            int b = (int)(xt * inv);
            b = (b < M_BKT - 1) ? b : (M_BKT - 1);

            // THE scattered load: 4 lanes of the quad hit the same 64B line
            float4 q = bl[(b << 2) + c];

            float xb = __shfl(q.z, gbase + 3);
            int   lo = __shfl(__float_as_int(q.w), gbase + 3);
            if (xt >= xb)                                    // ~12%, masked
                q = sl[((lo + 1) << 2) + c];

            float x0  = __shfl(q.z, gbase + 1);
            float idx = __shfl(q.w, gbase + 1);

            float s  = (xt - x0) * idx;
            float t1 = 1.0f - s;
            float s2 = s * s,   s4 = s2 * s2;
            float t2 = t1 * t1, t4 = t2 * t2;

            // lane c covers j0=2c (all 3 dims), j0+1 (all 3 dims split with
            // neighbors), per the line layout; weights w[j0], w[j0+1], (+w[j0+2])
            float v  = (c >= 2 ? s4 : 1.f) * ((c & 1) ? s2 : 1.f);  // s^(2c)
            float uu = (c < 2 ? t4 : 1.f) * ((c & 1) ? 1.f : t2);   // t^(6-2c)
            float cA = (c == 0) ? 1.f : ((c == 1) ? 21.f : ((c == 2) ? 35.f : 7.f));
            float cB = (c == 0) ? 7.f : ((c == 1) ? 35.f : ((c == 2) ? 21.f : 1.f));
            float wA = cA * v * (uu * t1);        // C(7,2c)   s^2c   t^(7-2c)
            float wB = cB * (v * s) * uu;         // C(7,2c+1) s^2c+1 t^(6-2c)

            float2 h0 = __half22float2(*reinterpret_cast<const __half2*>(&q.x));
            float2 h1 = __half22float2(*reinterpret_cast<const __half2*>(&q.y));
            float a0, a1, a2;
            if ((c & 1) == 0) {
                float wC = ((c == 0) ? 21.f : 7.f) * (v * s2) *
                           ((c < 2) ? t4 * t1 : t1);          // C(7,2c+2) s^2c+2 t^(5-2c)
                float2 h2 = __half22float2(*reinterpret_cast<const __half2*>(&q.z));
                float2 h3 = __half22float2(*reinterpret_cast<const __half2*>(&q.w));
                // [A0 A1 A2 B0 B1 B2 C0 C1]
                a0 = wA * h0.x;            a1 = wA * h0.y;            a2 = wA * h1.x;
                a0 = fmaf(wB, h1.y, a0);   a1 = fmaf(wB, h2.x, a1);   a2 = fmaf(wB, h2.y, a2);
                a0 = fmaf(wC, h3.x, a0);   a1 = fmaf(wC, h3.y, a1);
            } else {
                // [A2 B0 B1 B2]
                a2 = wA * h0.x;
                a0 = wB * h0.y;            a1 = wB * h1.x;            a2 = fmaf(wB, h1.y, a2);
            }

            // quad reduce (stays inside the aligned 4-lane group)
            a0 += __shfl_xor(a0, 1);  a0 += __shfl_xor(a0, 2);
            a1 += __shfl_xor(a1, 1);  a1 += __shfl_xor(a1, 2);
            a2 += __shfl_xor(a2, 1);  a2 += __shfl_xor(a2, 2);

            if (e < n && c < 3)
                out[e * 3 + c] = (c == 0) ? a0 : ((c == 1) ? a1 : a2);
        }
    }
}

// Fallback (ws too small): LDS binary search, f32 cp straight from inputs.
__global__ __launch_bounds__(256) void bezier_eval_fallback(
    const float* __restrict__ x,
    const float* __restrict__ cp,
    const float* __restrict__ xe,
    float* __restrict__ out,
    int n)
{
    __shared__ float xs[K_SEG + 1];
    for (int i = threadIdx.x; i < K_SEG + 1; i += blockDim.x) xs[i] = x[i];
    __syncthreads();
    const float xlast = xs[K_SEG];
    const int tstride = gridDim.x * blockDim.x;
    for (int i = blockIdx.x * blockDim.x + threadIdx.x; i < n; i += tstride) {
        float xt = fmodf(xe[i], xlast);
        int lo = 0, hi = K_SEG - 1;
        while (lo < hi) {
            int mid = (lo + hi + 1) >> 1;
            if (xs[mid] <= xt) lo = mid; else hi = mid - 1;
        }
        int seg = lo;
        float x0 = xs[seg];
        float s  = (xt - x0) / (xs[seg + 1] - x0);
        float ts = 1.0f - s;
        float comb[8] = {1.f, 7.f, 21.f, 35.f, 35.f, 21.f, 7.f, 1.f};
        float a0 = 0.f, a1 = 0.f, a2 = 0.f;
        float sp = 1.f;
        float tp[8];
        tp[7] = 1.f;
        for (int j = 6; j >= 0; --j) tp[j] = tp[j + 1] * ts;
        for (int j = 0; j < 8; ++j) {
            float wj = comb[j] * sp * tp[j];
            a0 = fmaf(wj, cp[seg * 24 + j * 3 + 0], a0);
            a1 = fmaf(wj, cp[seg * 24 + j * 3 + 1], a1);
            a2 = fmaf(wj, cp[seg * 24 + j * 3 + 2], a2);
            sp *= s;
        }
        out[i * 3 + 0] = a0;
        out[i * 3 + 1] = a1;
        out[i * 3 + 2] = a2;
    }
}

extern "C" void kernel_launch(void* const* d_in, const int* in_sizes, int n_in,
                              void* d_out, int out_size, void* d_ws, size_t ws_size,
                              hipStream_t stream) {
    const float* x  = (const float*)d_in[0];   // (K+1,)
    const float* cp = (const float*)d_in[1];   // (K, 8, 3)
    const float* xe = (const float*)d_in[2];   // (N_EVAL,)
    float* out = (float*)d_out;                // (N_EVAL, 3)
    int n = in_sizes[2];

    const size_t bl_bytes = (size_t)M_BKT * 64;   // 1 MB
    const size_t sl_bytes = (size_t)K_SEG * 64;   // 256 KB

    if (ws_size >= bl_bytes + sl_bytes) {
        float4* bline = (float4*)d_ws;
        float4* sline = (float4*)((char*)d_ws + bl_bytes);
        build_bline<<<(M_BKT + 255) / 256, 256, 0, stream>>>(x, cp, bline);
        build_segline<<<(K_SEG + 255) / 256, 256, 0, stream>>>(x, cp, sline);
        bezier_eval_coop<<<2048, 256, 0, stream>>>(x, bline, sline, xe, out, n);
    } else {
        bezier_eval_fallback<<<2048, 256, 0, stream>>>(x, cp, xe, out, n);
    }
}